// Round 8
// baseline (1071.952 us; speedup 1.0000x reference)
//
#include <hip/hip_runtime.h>
#include <hip/hip_bf16.h>
#include <stdint.h>

// ---------------------------------------------------------------------------
// MixModel fused kernel (MI355X / gfx950), round 8.
//
// Round-7 structure + deeper AGPR residency to zero the remaining scratch
// spill (round 7: VGPR capped at 256, ~1.3 GB spill traffic = ~100% of time).
// AGPR bank (238): msg1 (162) + msgc0/msgc1 snapshots (36) + stc (4) +
//                  msg0 rows 0-1 (36)
// VGPR bank (~211): msg0 rows 2-8 (126) + transients.
// All pins use v_accvgpr_write/read asm (proven round 7); MFMAs stay builtins
// (MAI hazards compiler-managed). Storage class split is compile-time (full
// unroll -> constant indices).
// ---------------------------------------------------------------------------

typedef __attribute__((ext_vector_type(4))) float    f32x4;
typedef __attribute__((ext_vector_type(4))) _Float16 f16x4;
typedef __attribute__((ext_vector_type(8))) _Float16 f16x8;
typedef __attribute__((ext_vector_type(2))) unsigned int u32x2;
typedef unsigned long long u64;
typedef unsigned int u32;

#define STEP_BYTES 55296           // 9 jt * 6 slices * 64 lanes * 16B
#define CMN_BYTES  45056           // padded; real 41472
#define WS_LAYER   (54*STEP_BYTES) // 2,985,984
#define LDS_TOTAL  (2*STEP_BYTES)  // 110,592

__device__ __forceinline__ unsigned short f2h(float f) {
  return __builtin_bit_cast(unsigned short, (_Float16)f);
}
__device__ __forceinline__ u64 as_u64(f16x4 v) { return __builtin_bit_cast(u64, v); }
__device__ __forceinline__ f16x4 as_f16x4(u64 v) { return __builtin_bit_cast(f16x4, v); }
__device__ __forceinline__ f16x4 pair_f16x4(u32 lo, u32 hi) {
  u32x2 w; w[0] = lo; w[1] = hi;
  return __builtin_bit_cast(f16x4, w);
}

__device__ __forceinline__ f32x4 mfma16(f16x4 a, f16x4 b, f32x4 c) {
#if __has_builtin(__builtin_amdgcn_mfma_f32_16x16x16f16)
  return __builtin_amdgcn_mfma_f32_16x16x16f16(a, b, c, 0, 0, 0);
#else
  asm("v_mfma_f32_16x16x16_f16 %0, %1, %2, %0" : "+v"(c) : "v"(a), "v"(b));
  return c;
#endif
}

// pin a 32-bit value into an AGPR (definition point); consumers are builtin
// MFMAs whose A/B operands accept AGPRs (AV class) on gfx90a+.
__device__ __forceinline__ u32 to_agpr(u32 v) {
  u32 r;
  asm("v_accvgpr_write_b32 %0, %1" : "=a"(r) : "v"(v));
  return r;
}
__device__ __forceinline__ u32 agpr_zero() {
  u32 r;
  asm("v_accvgpr_write_b32 %0, 0" : "=a"(r));
  return r;
}
// AGPR -> AGPR copy via an explicit VGPR bounce (only proven opcodes).
__device__ __forceinline__ u32 agpr_copy(u32 a) {
  u32 r, tmp;
  asm("v_accvgpr_read_b32 %1, %2\n\tv_accvgpr_write_b32 %0, %1"
      : "=a"(r), "=&v"(tmp) : "a"(a));
  return r;
}

// static feature value for (sample b, position o, padded k-index kidx in [0,48))
// [0..8] mask row o | [9..17] board ch0 row o | [18..26] board ch1 row o
// [27..35] g0 (ch0 row 9) | [36..44] g1 (ch1 row 9) | [45..47] zero pad
__device__ __forceinline__ float static_feat(const float* __restrict__ mask,
                                             const float* __restrict__ board,
                                             int b, int o, int kidx) {
  if (kidx < 9)  return mask [b*81  + o*9 + kidx];
  if (kidx < 18) return board[b*180 +       o*9 + (kidx - 9)];
  if (kidx < 27) return board[b*180 + 90 +  o*9 + (kidx - 18)];
  if (kidx < 36) return board[b*180 +       81 + (kidx - 27)];
  if (kidx < 45) return board[b*180 + 90 +  81 + (kidx - 36)];
  return 0.f;
}

// async stage one step's fragment block into LDS (wave-uniform dest + lane*16)
__device__ __forceinline__ void stage_step(int s, const unsigned char* __restrict__ ws,
                                           unsigned char* dstlds, int tid) {
  const unsigned char* src = (s < 54) ? (ws + (size_t)s * STEP_BYTES)
                                      : (ws + WS_LAYER + (size_t)(s - 54) * CMN_BYTES);
  const int n16 = (s < 54) ? (STEP_BYTES / 16) : (CMN_BYTES / 16);
  const int ubase = tid & ~63;
  for (int k = 0; k * 256 < n16; ++k) {
    const int idx = k * 256 + tid;
    if (idx < n16) {  // wave-uniform branch (n16 % 64 == 0)
      __builtin_amdgcn_global_load_lds(
          (const __attribute__((address_space(1))) void*)(src + (size_t)idx * 16),
          (__attribute__((address_space(3))) void*)(dstlds + (size_t)(k * 256 + ubase) * 16),
          16, 0, 0);
    }
  }
}

// tile-0 message read for compile-time (row, col): rows 0-1 in AGPR bank.
#define MSG0_FRAG(i, c) \
  ((i) < 2 ? pair_f16x4(msg0a[(i) < 2 ? (i) : 0][(c)][0], \
                        msg0a[(i) < 2 ? (i) : 0][(c)][1]) \
           : as_f16x4(msg0[(i) >= 2 ? (i) - 2 : 0][(c)]))

// one (layer, position) step: 9 jt output tiles, K=192 as 12 K16 chunks.
// chunk order: 0=st0(bits), 1=st1(bits), 2=stc(+bias lane), 3..11 = messages.
template<int P, int O>
__device__ __forceinline__ void do_position(const unsigned char* __restrict__ wb,
    u64 (&msg0)[7][9], u32 (&msg0a)[2][9][2], u32 (&msg1)[9][9][2],
    const u64 (&sb)[2], const u32 (&sb8)[2], const u32 (&stca)[2][2], int lane)
{
  // rebuild position-O static fragments from the bitmask bank (values 0/1)
  f16x4 st0[2], st1[2];
#pragma unroll
  for (int t = 0; t < 2; ++t) {
    const u32 byt = (O < 8) ? ((u32)(sb[t] >> (O * 8)) & 0xFFu) : sb8[t];
#pragma unroll
    for (int e = 0; e < 4; ++e) {
      st0[t][e] = (_Float16)(float)((byt >> e) & 1u);
      st1[t][e] = (_Float16)(float)((byt >> (4 + e)) & 1u);
    }
  }

  // snapshot the message chunks into AGPRs (read set == write set this step)
  u32 msgc0[9][2], msgc1[9][2];
#pragma unroll
  for (int i = 0; i < 9; ++i) {
    const int r = P ? O : i;
    const int c = P ? i : O;
    if (r < 2) {
      msgc0[i][0] = agpr_copy(msg0a[r < 2 ? r : 0][c][0]);
      msgc0[i][1] = agpr_copy(msg0a[r < 2 ? r : 0][c][1]);
    } else {
      const u32x2 w = __builtin_bit_cast(u32x2, msg0[r >= 2 ? r - 2 : 0][c]);
      msgc0[i][0] = to_agpr(w[0]);
      msgc0[i][1] = to_agpr(w[1]);
    }
    msgc1[i][0] = agpr_copy(msg1[r][c][0]);
    msgc1[i][1] = agpr_copy(msg1[r][c][1]);
  }

  const unsigned char* abase = wb + (size_t)lane * 16;
#pragma unroll
  for (int j = 0; j < 9; ++j) {
    f32x4 acc0 = 0.f, acc1 = 0.f;
#pragma unroll
    for (int sp = 0; sp < 6; ++sp) {
      const f16x8 af = *(const f16x8*)(abase + j * 6144 + sp * 1024);
      const f16x4 alo = __builtin_shufflevector(af, af, 0, 1, 2, 3);
      const f16x4 ahi = __builtin_shufflevector(af, af, 4, 5, 6, 7);
      const int c0 = 2 * sp, c1 = 2 * sp + 1;
      // even chunk (c0): 0 -> st0, 2 -> stc, else message chunk c0-3
      if (c0 == 0) {
        acc0 = mfma16(alo, st0[0], acc0);
        acc1 = mfma16(alo, st0[1], acc1);
      } else if (c0 == 2) {
        acc0 = mfma16(alo, pair_f16x4(stca[0][0], stca[0][1]), acc0);
        acc1 = mfma16(alo, pair_f16x4(stca[1][0], stca[1][1]), acc1);
      } else {
        acc0 = mfma16(alo, pair_f16x4(msgc0[c0 - 3][0], msgc0[c0 - 3][1]), acc0);
        acc1 = mfma16(alo, pair_f16x4(msgc1[c0 - 3][0], msgc1[c0 - 3][1]), acc1);
      }
      // odd chunk (c1): 1 -> st1, else message chunk c1-3
      if (c1 == 1) {
        acc0 = mfma16(ahi, st1[0], acc0);
        acc1 = mfma16(ahi, st1[1], acc1);
      } else {
        acc0 = mfma16(ahi, pair_f16x4(msgc0[c1 - 3][0], msgc0[c1 - 3][1]), acc0);
        acc1 = mfma16(ahi, pair_f16x4(msgc1[c1 - 3][0], msgc1[c1 - 3][1]), acc1);
      }
    }
    f16x4 h0, h1;
#pragma unroll
    for (int r = 0; r < 4; ++r) {
      h0[r] = (_Float16)fmaxf(acc0[r], 0.f);
      h1[r] = (_Float16)fmaxf(acc1[r], 0.f);
    }
    const int r = P ? O : j;
    const int c = P ? j : O;
    if (r < 2) {
      const u32x2 h0w = __builtin_bit_cast(u32x2, h0);
      msg0a[r < 2 ? r : 0][c][0] = to_agpr(h0w[0]);
      msg0a[r < 2 ? r : 0][c][1] = to_agpr(h0w[1]);
    } else {
      msg0[r >= 2 ? r - 2 : 0][c] = as_u64(h0);
    }
    const u32x2 h1w = __builtin_bit_cast(u32x2, h1);
    msg1[r][c][0] = to_agpr(h1w[0]);
    msg1[r][c][1] = to_agpr(h1w[1]);
  }
}

__global__ __launch_bounds__(256, 1) void mix_main(
    const float* __restrict__ mask, const float* __restrict__ board,
    const float* __restrict__ common_b, const float* __restrict__ wdl_w,
    const float* __restrict__ wdl_b, const unsigned char* __restrict__ ws,
    float* __restrict__ out, int Bt)
{
  extern __shared__ unsigned char lds[];
  const int tid = threadIdx.x;
  const int lane = tid & 63;
  const int wid = tid >> 6;
  const int s15 = lane & 15, hq = lane >> 4;
  const int b0 = blockIdx.x * 128 + wid * 32;

  stage_step(0, ws, lds, tid);   // prologue stage of step 0 (buffer parity 0)

  u64 msg0[7][9];        // tile-0 messages, rows 2-8 (VGPR)
  u32 msg0a[2][9][2];    // tile-0 messages, rows 0-1 (AGPR)
  u32 msg1[9][9][2];     // tile-1 messages (AGPR)
#pragma unroll
  for (int a = 0; a < 7; ++a)
#pragma unroll
    for (int b = 0; b < 9; ++b) msg0[a][b] = 0ull;
#pragma unroll
  for (int a = 0; a < 2; ++a)
#pragma unroll
    for (int b = 0; b < 9; ++b) { msg0a[a][b][0] = agpr_zero(); msg0a[a][b][1] = agpr_zero(); }
#pragma unroll
  for (int a = 0; a < 9; ++a)
#pragma unroll
    for (int b = 0; b < 9; ++b) { msg1[a][b][0] = agpr_zero(); msg1[a][b][1] = agpr_zero(); }

  // static bitmask bank: bit (o*8 + c*4 + e) of sb[t] (o<8) / sb8[t] (o=8)
  // holds static_feat(b, o, c*16 + 4*hq + e) — all mask/board values are 0/1.
  u64 sb[2] = {0ull, 0ull};
  u32 sb8[2] = {0u, 0u};
#pragma unroll
  for (int t = 0; t < 2; ++t) {
    const int b = b0 + t * 16 + s15;
#pragma unroll
    for (int o = 0; o < 9; ++o)
#pragma unroll
      for (int e = 0; e < 4; ++e) {
        const u32 bit0 = static_feat(mask, board, b, o,      4 * hq + e) > 0.5f;
        const u32 bit1 = static_feat(mask, board, b, o, 16 + 4 * hq + e) > 0.5f;
        if (o < 8) sb[t] |= ((u64)bit0 << (o * 8 + e)) | ((u64)bit1 << (o * 8 + 4 + e));
        else       sb8[t] |= (bit0 << e) | (bit1 << (4 + e));
      }
  }

  // position-independent chunk 2 (g0 tail + g1); pad lane k=45 carries 1.0
  // so the layer bias (stored in weight row 45) rides the MFMA. AGPR-pinned.
  u32 stca[2][2];
#pragma unroll
  for (int t = 0; t < 2; ++t) {
    const int b = b0 + t * 16 + s15;
    f16x4 stc;
#pragma unroll
    for (int e = 0; e < 4; ++e) {
      const int kidx = 32 + 4 * hq + e;
      stc[e] = (_Float16)((kidx == 45) ? 1.f : static_feat(mask, board, b, 0, kidx));
    }
    const u32x2 w = __builtin_bit_cast(u32x2, stc);
    stca[t][0] = to_agpr(w[0]);
    stca[t][1] = to_agpr(w[1]);
  }

#define DO_POS(P, O) { \
    asm volatile("s_waitcnt vmcnt(0)" ::: "memory"); \
    __syncthreads(); \
    const int step = base + (P) * 9 + (O); \
    if (step + 1 < 64) \
      stage_step(step + 1, ws, lds + (size_t)((step + 1) & 1) * STEP_BYTES, tid); \
    do_position<P, O>(lds + (size_t)(step & 1) * STEP_BYTES, msg0, msg0a, msg1, \
                      sb, sb8, stca, lane); \
  }

  for (int dp = 0; dp < 3; ++dp) {
    const int base = dp * 18;
    DO_POS(0,0) DO_POS(0,1) DO_POS(0,2) DO_POS(0,3) DO_POS(0,4)
    DO_POS(0,5) DO_POS(0,6) DO_POS(0,7) DO_POS(0,8)
    DO_POS(1,0) DO_POS(1,1) DO_POS(1,2) DO_POS(1,3) DO_POS(1,4)
    DO_POS(1,5) DO_POS(1,6) DO_POS(1,7) DO_POS(1,8)
  }
#undef DO_POS

  // ---- common layer: (B x 1296) @ (1296 x 145), 10 M-tiles streamed ----
  float pw0[3] = {0.f, 0.f, 0.f}, pw1[3] = {0.f, 0.f, 0.f};
  for (int mt = 0; mt < 10; ++mt) {
    asm volatile("s_waitcnt vmcnt(0)" ::: "memory");
    __syncthreads();
    const int step = 54 + mt;
    if (step + 1 < 64)
      stage_step(step + 1, ws, lds + (size_t)((step + 1) & 1) * STEP_BYTES, tid);
    const unsigned char* cb = lds + (size_t)(step & 1) * STEP_BYTES;
    f32x4 a0 = 0.f, a1 = 0.f;
#pragma unroll
    for (int i = 0; i < 9; ++i) {
#pragma unroll
      for (int p = 0; p < 4; ++p) {
        const f16x8 af = *(const f16x8*)(cb + ((size_t)(i * 4 + p) * 64 + lane) * 16);
        const f16x4 alo = __builtin_shufflevector(af, af, 0, 1, 2, 3);
        const f16x4 ahi = __builtin_shufflevector(af, af, 4, 5, 6, 7);
        a0 = mfma16(alo, MSG0_FRAG(i, 2 * p), a0);
        a1 = mfma16(alo, pair_f16x4(msg1[i][2 * p][0], msg1[i][2 * p][1]), a1);
        a0 = mfma16(ahi, MSG0_FRAG(i, 2 * p + 1), a0);
        a1 = mfma16(ahi, pair_f16x4(msg1[i][2 * p + 1][0], msg1[i][2 * p + 1][1]), a1);
      }
      const f16x4 al = *(const f16x4*)(cb + 36864 + ((size_t)i * 64 + lane) * 8);
      a0 = mfma16(al, MSG0_FRAG(i, 8), a0);
      a1 = mfma16(al, pair_f16x4(msg1[i][8][0], msg1[i][8][1]), a1);
    }
#pragma unroll
    for (int r = 0; r < 4; ++r) {
      const int c = mt * 16 + 4 * hq + r;
      const float bias = (c < 145) ? common_b[c] : 0.f;
      const float v0 = a0[r] + bias, v1 = a1[r] + bias;
      if (c < 81) {  // policy (no relu)
        out[(size_t)3 * Bt + (size_t)(b0 + s15) * 81 + c]      = v0;
        out[(size_t)3 * Bt + (size_t)(b0 + 16 + s15) * 81 + c] = v1;
      } else if (c < 145) {  // wdl hidden: relu then tiny matmul accumulation
        const float h0 = fmaxf(v0, 0.f), h1 = fmaxf(v1, 0.f);
        const int cc = c - 81;
#pragma unroll
        for (int w = 0; w < 3; ++w) {
          const float wv = wdl_w[cc * 3 + w];
          pw0[w] += h0 * wv;
          pw1[w] += h1 * wv;
        }
      }
    }
  }

  // reduce wdl partials across the 4 lane-quarters (same sample col)
#pragma unroll
  for (int w = 0; w < 3; ++w) {
    float v0 = pw0[w], v1 = pw1[w];
    v0 += __shfl_xor(v0, 16, 64); v0 += __shfl_xor(v0, 32, 64);
    v1 += __shfl_xor(v1, 16, 64); v1 += __shfl_xor(v1, 32, 64);
    if (hq == 0) {
      const float bb = wdl_b[w];
      out[(size_t)(b0 + s15) * 3 + w]      = v0 + bb;
      out[(size_t)(b0 + 16 + s15) * 3 + w] = v1 + bb;
    }
  }
}

// ---- prologue: layer weights -> fp16 A-fragment order -----------------------
// [d*9+o][jt 9][slice 6][lane 64] x 16B ; e<4 -> kc=2s, e>=4 -> kc=2s+1,
// within-chunk k = 4*hq + (e&3). kidx: 0..44 static, 45 = BIAS row, 46..47
// zero, >=48 -> message k = kidx-3.
__global__ __launch_bounds__(256) void conv_layer_w(const float* __restrict__ lw,
                                                    const float* __restrict__ lb,
                                                    unsigned char* __restrict__ dst) {
  const int gid = blockIdx.x * 256 + threadIdx.x;
  if (gid >= 54 * 9 * 6 * 64) return;
  const int lane = gid & 63;
  const int t = gid >> 6;
  const int kp = t % 6, t2 = t / 6;
  const int jp = t2 % 9, dop = t2 / 9;
  const int m = lane & 15, hq = lane >> 4;
  unsigned short v[8];
#pragma unroll
  for (int e = 0; e < 8; ++e) {
    const int kc = kp * 2 + (e >> 2);
    const int kidx = kc * 16 + 4 * hq + (e & 3);
    float f = 0.f;
    if (kidx < 45)        f = lw[((size_t)dop * 189 + kidx) * 144 + jp * 16 + m];
    else if (kidx == 45)  f = lb[(size_t)dop * 144 + jp * 16 + m];
    else if (kidx >= 48)  f = lw[((size_t)dop * 189 + (kidx - 3)) * 144 + jp * 16 + m];
    v[e] = f2h(f);
  }
  const u32 w0 = (u32)v[0] | ((u32)v[1] << 16);
  const u32 w1 = (u32)v[2] | ((u32)v[3] << 16);
  const u32 w2 = (u32)v[4] | ((u32)v[5] << 16);
  const u32 w3 = (u32)v[6] | ((u32)v[7] << 16);
  *(uint4*)(dst + (size_t)gid * 16) = make_uint4(w0, w1, w2, w3);
}

// ---- prologue: common weights -> fp16 A-fragment order ----------------------
// per mt: [(i*4+p)*64+lane]x16B (pairs ci=i*9+2p, i*9+2p+1), then at 36864:
// [i*64+lane]x8B (leftover ci=i*9+8). c_out padded 145->160 with zeros.
__global__ __launch_bounds__(256) void conv_common_w(const float* __restrict__ cw,
                                                     unsigned char* __restrict__ dst) {
  const int gid = blockIdx.x * 256 + threadIdx.x;
  const int NPAIR = 10 * 36 * 64;
  if (gid < NPAIR) {
    const int lane = gid & 63;
    const int t = gid >> 6;
    const int p = t % 4, t2 = t / 4;
    const int i = t2 % 9, mt = t2 / 9;
    const int m = lane & 15, hq = lane >> 4;
    const int c = mt * 16 + m;
    unsigned short v[8];
#pragma unroll
    for (int e = 0; e < 8; ++e) {
      const int ci = i * 9 + 2 * p + (e >> 2);
      const int k = ci * 16 + 4 * hq + (e & 3);
      v[e] = f2h((c < 145) ? cw[(size_t)k * 145 + c] : 0.f);
    }
    const u32 w0 = (u32)v[0] | ((u32)v[1] << 16);
    const u32 w1 = (u32)v[2] | ((u32)v[3] << 16);
    const u32 w2 = (u32)v[4] | ((u32)v[5] << 16);
    const u32 w3 = (u32)v[6] | ((u32)v[7] << 16);
    *(uint4*)(dst + (size_t)WS_LAYER + (size_t)mt * CMN_BYTES
              + ((size_t)(i * 4 + p) * 64 + lane) * 16) = make_uint4(w0, w1, w2, w3);
  } else if (gid < NPAIR + 10 * 9 * 64) {
    const int g = gid - NPAIR;
    const int lane = g & 63;
    const int t = g >> 6;
    const int i = t % 9, mt = t / 9;
    const int m = lane & 15, hq = lane >> 4;
    const int c = mt * 16 + m;
    unsigned short v[4];
#pragma unroll
    for (int e = 0; e < 4; ++e) {
      const int k = (i * 9 + 8) * 16 + 4 * hq + e;
      v[e] = f2h((c < 145) ? cw[(size_t)k * 145 + c] : 0.f);
    }
    const u32 w0 = (u32)v[0] | ((u32)v[1] << 16);
    const u32 w1 = (u32)v[2] | ((u32)v[3] << 16);
    *(uint2*)(dst + (size_t)WS_LAYER + (size_t)mt * CMN_BYTES + 36864
              + ((size_t)i * 64 + lane) * 8) = make_uint2(w0, w1);
  }
}

extern "C" void kernel_launch(void* const* d_in, const int* in_sizes, int n_in,
                              void* d_out, int out_size, void* d_ws, size_t ws_size,
                              hipStream_t stream) {
  const float* mask     = (const float*)d_in[0];
  const float* board    = (const float*)d_in[1];
  const float* layer_w  = (const float*)d_in[2];
  const float* layer_b  = (const float*)d_in[3];
  const float* common_w = (const float*)d_in[4];
  const float* common_b = (const float*)d_in[5];
  const float* wdl_w    = (const float*)d_in[6];
  const float* wdl_b    = (const float*)d_in[7];
  float* out = (float*)d_out;
  unsigned char* ws = (unsigned char*)d_ws;
  const int Bt = in_sizes[0] / 81;   // 65536

  hipLaunchKernelGGL(conv_layer_w, dim3((54 * 9 * 6 * 64) / 256), dim3(256), 0, stream,
                     layer_w, layer_b, ws);
  hipLaunchKernelGGL(conv_common_w, dim3((10 * (36 + 9) * 64 + 255) / 256), dim3(256),
                     0, stream, common_w, ws);
  (void)hipFuncSetAttribute((const void*)mix_main,
                            hipFuncAttributeMaxDynamicSharedMemorySize, LDS_TOTAL);
  hipLaunchKernelGGL(mix_main, dim3(Bt / 128), dim3(256), LDS_TOTAL, stream,
                     mask, board, common_b, wdl_w, wdl_b, ws, out, Bt);
}

// Round 9
// 898.968 us; speedup vs baseline: 1.1924x; 1.1924x over previous
//
#include <hip/hip_runtime.h>
#include <hip/hip_bf16.h>
#include <stdint.h>

// ---------------------------------------------------------------------------
// MixModel fused kernel (MI355X / gfx950), round 9.
//
// Lesson from r5-r8: the 2-tile (32 samples/wave) message bank (324 regs)
// cannot be allocated without scratch spill (compiler caps arch VGPRs at 256
// and won't migrate to AGPRs; explicit pins trade spill for copy chains).
// This round: ONE 16-sample tile per wave -> message bank 162 VGPRs, total
// live ~225 <= 256, zero spill, zero AGPR asm. Same total MFMA work (2x
// waves); LDS A-panel reads and weight staging double (L2-resident, fits).
// - messages (9x9 chunks) resident in VGPRs; C/D frag == B frag => free
//   inter-layer transpose via alternating parity (round-2/4/5 proven).
// - static features as per-lane bitmask bank (5 regs), rebuilt per step.
// - layer bias folded into weight row k=45 (pad lane carries 1.0).
// - weights stream global->LDS via global_load_lds, double-buffered.
// ---------------------------------------------------------------------------

typedef __attribute__((ext_vector_type(4))) float    f32x4;
typedef __attribute__((ext_vector_type(4))) _Float16 f16x4;
typedef __attribute__((ext_vector_type(8))) _Float16 f16x8;
typedef unsigned long long u64;
typedef unsigned int u32;

#define STEP_BYTES 55296           // 9 jt * 6 slices * 64 lanes * 16B
#define CMN_BYTES  45056           // padded; real 41472
#define WS_LAYER   (54*STEP_BYTES) // 2,985,984
#define LDS_TOTAL  (2*STEP_BYTES)  // 110,592

__device__ __forceinline__ unsigned short f2h(float f) {
  return __builtin_bit_cast(unsigned short, (_Float16)f);
}
__device__ __forceinline__ u64 as_u64(f16x4 v) { return __builtin_bit_cast(u64, v); }
__device__ __forceinline__ f16x4 as_f16x4(u64 v) { return __builtin_bit_cast(f16x4, v); }

__device__ __forceinline__ f32x4 mfma16(f16x4 a, f16x4 b, f32x4 c) {
#if __has_builtin(__builtin_amdgcn_mfma_f32_16x16x16f16)
  return __builtin_amdgcn_mfma_f32_16x16x16f16(a, b, c, 0, 0, 0);
#else
  asm("v_mfma_f32_16x16x16_f16 %0, %1, %2, %0" : "+v"(c) : "v"(a), "v"(b));
  return c;
#endif
}

// static feature value for (sample b, position o, padded k-index kidx in [0,48))
// [0..8] mask row o | [9..17] board ch0 row o | [18..26] board ch1 row o
// [27..35] g0 (ch0 row 9) | [36..44] g1 (ch1 row 9) | [45..47] zero pad
__device__ __forceinline__ float static_feat(const float* __restrict__ mask,
                                             const float* __restrict__ board,
                                             int b, int o, int kidx) {
  if (kidx < 9)  return mask [b*81  + o*9 + kidx];
  if (kidx < 18) return board[b*180 +       o*9 + (kidx - 9)];
  if (kidx < 27) return board[b*180 + 90 +  o*9 + (kidx - 18)];
  if (kidx < 36) return board[b*180 +       81 + (kidx - 27)];
  if (kidx < 45) return board[b*180 + 90 +  81 + (kidx - 36)];
  return 0.f;
}

// async stage one step's fragment block into LDS (wave-uniform dest + lane*16)
__device__ __forceinline__ void stage_step(int s, const unsigned char* __restrict__ ws,
                                           unsigned char* dstlds, int tid) {
  const unsigned char* src = (s < 54) ? (ws + (size_t)s * STEP_BYTES)
                                      : (ws + WS_LAYER + (size_t)(s - 54) * CMN_BYTES);
  const int n16 = (s < 54) ? (STEP_BYTES / 16) : (CMN_BYTES / 16);
  const int ubase = tid & ~63;
  for (int k = 0; k * 256 < n16; ++k) {
    const int idx = k * 256 + tid;
    if (idx < n16) {  // wave-uniform branch (n16 % 64 == 0)
      __builtin_amdgcn_global_load_lds(
          (const __attribute__((address_space(1))) void*)(src + (size_t)idx * 16),
          (__attribute__((address_space(3))) void*)(dstlds + (size_t)(k * 256 + ubase) * 16),
          16, 0, 0);
    }
  }
}

// one (layer, position) step: 9 jt output tiles, K=192 as 12 K16 chunks.
// chunk order: 0=st0(bits), 1=st1(bits), 2=stc(+bias lane), 3..11 = messages.
template<int P, int O>
__device__ __forceinline__ void do_position(const unsigned char* __restrict__ wb,
    u64 (&msg)[9][9], const u64 sb, const u32 sb8, const f16x4 stc, int lane)
{
  // rebuild position-O static fragments from the bitmask bank (values 0/1)
  f16x4 st0, st1;
  {
    const u32 byt = (O < 8) ? ((u32)(sb >> (O * 8)) & 0xFFu) : sb8;
#pragma unroll
    for (int e = 0; e < 4; ++e) {
      st0[e] = (_Float16)(float)((byt >> e) & 1u);
      st1[e] = (_Float16)(float)((byt >> (4 + e)) & 1u);
    }
  }

  // snapshot the message chunks (read set == write set within this step)
  u64 msgc[9];
#pragma unroll
  for (int i = 0; i < 9; ++i)
    msgc[i] = P ? msg[O][i] : msg[i][O];

  const unsigned char* abase = wb + (size_t)lane * 16;
#pragma unroll
  for (int j = 0; j < 9; ++j) {
    f32x4 acc = 0.f;
#pragma unroll
    for (int sp = 0; sp < 6; ++sp) {
      const f16x8 af = *(const f16x8*)(abase + j * 6144 + sp * 1024);
      const f16x4 alo = __builtin_shufflevector(af, af, 0, 1, 2, 3);
      const f16x4 ahi = __builtin_shufflevector(af, af, 4, 5, 6, 7);
      const int c0 = 2 * sp, c1 = 2 * sp + 1;
      // even chunk (c0): 0 -> st0, 2 -> stc, else message chunk c0-3
      if (c0 == 0)      acc = mfma16(alo, st0, acc);
      else if (c0 == 2) acc = mfma16(alo, stc, acc);
      else              acc = mfma16(alo, as_f16x4(msgc[c0 - 3]), acc);
      // odd chunk (c1): 1 -> st1, else message chunk c1-3
      if (c1 == 1)      acc = mfma16(ahi, st1, acc);
      else              acc = mfma16(ahi, as_f16x4(msgc[c1 - 3]), acc);
    }
    f16x4 h;
#pragma unroll
    for (int r = 0; r < 4; ++r)
      h[r] = (_Float16)fmaxf(acc[r], 0.f);
    if (P) msg[O][j] = as_u64(h); else msg[j][O] = as_u64(h);
  }
}

__global__ __launch_bounds__(256, 1) void mix_main(
    const float* __restrict__ mask, const float* __restrict__ board,
    const float* __restrict__ common_b, const float* __restrict__ wdl_w,
    const float* __restrict__ wdl_b, const unsigned char* __restrict__ ws,
    float* __restrict__ out, int Bt)
{
  extern __shared__ unsigned char lds[];
  const int tid = threadIdx.x;
  const int lane = tid & 63;
  const int wid = tid >> 6;
  const int s15 = lane & 15, hq = lane >> 4;
  const int b0 = blockIdx.x * 64 + wid * 16;   // 16 samples per wave

  stage_step(0, ws, lds, tid);   // prologue stage of step 0 (buffer parity 0)

  u64 msg[9][9];
#pragma unroll
  for (int a = 0; a < 9; ++a)
#pragma unroll
    for (int b = 0; b < 9; ++b) msg[a][b] = 0ull;

  // static bitmask bank: bit (o*8 + c*4 + e) of sb (o<8) / sb8 (o=8)
  // holds static_feat(b, o, c*16 + 4*hq + e) — all mask/board values are 0/1.
  u64 sb = 0ull;
  u32 sb8 = 0u;
  {
    const int b = b0 + s15;
#pragma unroll
    for (int o = 0; o < 9; ++o)
#pragma unroll
      for (int e = 0; e < 4; ++e) {
        const u32 bit0 = static_feat(mask, board, b, o,      4 * hq + e) > 0.5f;
        const u32 bit1 = static_feat(mask, board, b, o, 16 + 4 * hq + e) > 0.5f;
        if (o < 8) sb |= ((u64)bit0 << (o * 8 + e)) | ((u64)bit1 << (o * 8 + 4 + e));
        else       sb8 |= (bit0 << e) | (bit1 << (4 + e));
      }
  }

  // position-independent chunk 2 (g0 tail + g1); pad lane k=45 carries 1.0
  // so the layer bias (stored in weight row 45) rides the MFMA.
  f16x4 stc;
  {
    const int b = b0 + s15;
#pragma unroll
    for (int e = 0; e < 4; ++e) {
      const int kidx = 32 + 4 * hq + e;
      stc[e] = (_Float16)((kidx == 45) ? 1.f : static_feat(mask, board, b, 0, kidx));
    }
  }

#define DO_POS(P, O) { \
    asm volatile("s_waitcnt vmcnt(0)" ::: "memory"); \
    __syncthreads(); \
    const int step = base + (P) * 9 + (O); \
    if (step + 1 < 64) \
      stage_step(step + 1, ws, lds + (size_t)((step + 1) & 1) * STEP_BYTES, tid); \
    do_position<P, O>(lds + (size_t)(step & 1) * STEP_BYTES, msg, sb, sb8, stc, lane); \
  }

  for (int dp = 0; dp < 3; ++dp) {
    const int base = dp * 18;
    DO_POS(0,0) DO_POS(0,1) DO_POS(0,2) DO_POS(0,3) DO_POS(0,4)
    DO_POS(0,5) DO_POS(0,6) DO_POS(0,7) DO_POS(0,8)
    DO_POS(1,0) DO_POS(1,1) DO_POS(1,2) DO_POS(1,3) DO_POS(1,4)
    DO_POS(1,5) DO_POS(1,6) DO_POS(1,7) DO_POS(1,8)
  }
#undef DO_POS

  // ---- common layer: (B x 1296) @ (1296 x 145), 10 M-tiles streamed ----
  float pw[3] = {0.f, 0.f, 0.f};
  for (int mt = 0; mt < 10; ++mt) {
    asm volatile("s_waitcnt vmcnt(0)" ::: "memory");
    __syncthreads();
    const int step = 54 + mt;
    if (step + 1 < 64)
      stage_step(step + 1, ws, lds + (size_t)((step + 1) & 1) * STEP_BYTES, tid);
    const unsigned char* cb = lds + (size_t)(step & 1) * STEP_BYTES;
    f32x4 a0 = 0.f;
#pragma unroll
    for (int i = 0; i < 9; ++i) {
#pragma unroll
      for (int p = 0; p < 4; ++p) {
        const f16x8 af = *(const f16x8*)(cb + ((size_t)(i * 4 + p) * 64 + lane) * 16);
        const f16x4 alo = __builtin_shufflevector(af, af, 0, 1, 2, 3);
        const f16x4 ahi = __builtin_shufflevector(af, af, 4, 5, 6, 7);
        a0 = mfma16(alo, as_f16x4(msg[i][2 * p]),     a0);
        a0 = mfma16(ahi, as_f16x4(msg[i][2 * p + 1]), a0);
      }
      const f16x4 al = *(const f16x4*)(cb + 36864 + ((size_t)i * 64 + lane) * 8);
      a0 = mfma16(al, as_f16x4(msg[i][8]), a0);
    }
#pragma unroll
    for (int r = 0; r < 4; ++r) {
      const int c = mt * 16 + 4 * hq + r;
      const float bias = (c < 145) ? common_b[c] : 0.f;
      const float v0 = a0[r] + bias;
      if (c < 81) {  // policy (no relu)
        out[(size_t)3 * Bt + (size_t)(b0 + s15) * 81 + c] = v0;
      } else if (c < 145) {  // wdl hidden: relu then tiny matmul accumulation
        const float h0 = fmaxf(v0, 0.f);
        const int cc = c - 81;
#pragma unroll
        for (int w = 0; w < 3; ++w)
          pw[w] += h0 * wdl_w[cc * 3 + w];
      }
    }
  }

  // reduce wdl partials across the 4 lane-quarters (same sample col)
#pragma unroll
  for (int w = 0; w < 3; ++w) {
    float v0 = pw[w];
    v0 += __shfl_xor(v0, 16, 64); v0 += __shfl_xor(v0, 32, 64);
    if (hq == 0)
      out[(size_t)(b0 + s15) * 3 + w] = v0 + wdl_b[w];
  }
}

// ---- prologue: layer weights -> fp16 A-fragment order -----------------------
// [d*9+o][jt 9][slice 6][lane 64] x 16B ; e<4 -> kc=2s, e>=4 -> kc=2s+1,
// within-chunk k = 4*hq + (e&3). kidx: 0..44 static, 45 = BIAS row, 46..47
// zero, >=48 -> message k = kidx-3.
__global__ __launch_bounds__(256) void conv_layer_w(const float* __restrict__ lw,
                                                    const float* __restrict__ lb,
                                                    unsigned char* __restrict__ dst) {
  const int gid = blockIdx.x * 256 + threadIdx.x;
  if (gid >= 54 * 9 * 6 * 64) return;
  const int lane = gid & 63;
  const int t = gid >> 6;
  const int kp = t % 6, t2 = t / 6;
  const int jp = t2 % 9, dop = t2 / 9;
  const int m = lane & 15, hq = lane >> 4;
  unsigned short v[8];
#pragma unroll
  for (int e = 0; e < 8; ++e) {
    const int kc = kp * 2 + (e >> 2);
    const int kidx = kc * 16 + 4 * hq + (e & 3);
    float f = 0.f;
    if (kidx < 45)        f = lw[((size_t)dop * 189 + kidx) * 144 + jp * 16 + m];
    else if (kidx == 45)  f = lb[(size_t)dop * 144 + jp * 16 + m];
    else if (kidx >= 48)  f = lw[((size_t)dop * 189 + (kidx - 3)) * 144 + jp * 16 + m];
    v[e] = f2h(f);
  }
  const u32 w0 = (u32)v[0] | ((u32)v[1] << 16);
  const u32 w1 = (u32)v[2] | ((u32)v[3] << 16);
  const u32 w2 = (u32)v[4] | ((u32)v[5] << 16);
  const u32 w3 = (u32)v[6] | ((u32)v[7] << 16);
  *(uint4*)(dst + (size_t)gid * 16) = make_uint4(w0, w1, w2, w3);
}

// ---- prologue: common weights -> fp16 A-fragment order ----------------------
// per mt: [(i*4+p)*64+lane]x16B (pairs ci=i*9+2p, i*9+2p+1), then at 36864:
// [i*64+lane]x8B (leftover ci=i*9+8). c_out padded 145->160 with zeros.
__global__ __launch_bounds__(256) void conv_common_w(const float* __restrict__ cw,
                                                     unsigned char* __restrict__ dst) {
  const int gid = blockIdx.x * 256 + threadIdx.x;
  const int NPAIR = 10 * 36 * 64;
  if (gid < NPAIR) {
    const int lane = gid & 63;
    const int t = gid >> 6;
    const int p = t % 4, t2 = t / 4;
    const int i = t2 % 9, mt = t2 / 9;
    const int m = lane & 15, hq = lane >> 4;
    const int c = mt * 16 + m;
    unsigned short v[8];
#pragma unroll
    for (int e = 0; e < 8; ++e) {
      const int ci = i * 9 + 2 * p + (e >> 2);
      const int k = ci * 16 + 4 * hq + (e & 3);
      v[e] = f2h((c < 145) ? cw[(size_t)k * 145 + c] : 0.f);
    }
    const u32 w0 = (u32)v[0] | ((u32)v[1] << 16);
    const u32 w1 = (u32)v[2] | ((u32)v[3] << 16);
    const u32 w2 = (u32)v[4] | ((u32)v[5] << 16);
    const u32 w3 = (u32)v[6] | ((u32)v[7] << 16);
    *(uint4*)(dst + (size_t)WS_LAYER + (size_t)mt * CMN_BYTES
              + ((size_t)(i * 4 + p) * 64 + lane) * 16) = make_uint4(w0, w1, w2, w3);
  } else if (gid < NPAIR + 10 * 9 * 64) {
    const int g = gid - NPAIR;
    const int lane = g & 63;
    const int t = g >> 6;
    const int i = t % 9, mt = t / 9;
    const int m = lane & 15, hq = lane >> 4;
    const int c = mt * 16 + m;
    unsigned short v[4];
#pragma unroll
    for (int e = 0; e < 4; ++e) {
      const int k = (i * 9 + 8) * 16 + 4 * hq + e;
      v[e] = f2h((c < 145) ? cw[(size_t)k * 145 + c] : 0.f);
    }
    const u32 w0 = (u32)v[0] | ((u32)v[1] << 16);
    const u32 w1 = (u32)v[2] | ((u32)v[3] << 16);
    *(uint2*)(dst + (size_t)WS_LAYER + (size_t)mt * CMN_BYTES + 36864
              + ((size_t)i * 64 + lane) * 8) = make_uint2(w0, w1);
  }
}

extern "C" void kernel_launch(void* const* d_in, const int* in_sizes, int n_in,
                              void* d_out, int out_size, void* d_ws, size_t ws_size,
                              hipStream_t stream) {
  const float* mask     = (const float*)d_in[0];
  const float* board    = (const float*)d_in[1];
  const float* layer_w  = (const float*)d_in[2];
  const float* layer_b  = (const float*)d_in[3];
  const float* common_w = (const float*)d_in[4];
  const float* common_b = (const float*)d_in[5];
  const float* wdl_w    = (const float*)d_in[6];
  const float* wdl_b    = (const float*)d_in[7];
  float* out = (float*)d_out;
  unsigned char* ws = (unsigned char*)d_ws;
  const int Bt = in_sizes[0] / 81;   // 65536

  hipLaunchKernelGGL(conv_layer_w, dim3((54 * 9 * 6 * 64) / 256), dim3(256), 0, stream,
                     layer_w, layer_b, ws);
  hipLaunchKernelGGL(conv_common_w, dim3((10 * (36 + 9) * 64 + 255) / 256), dim3(256),
                     0, stream, common_w, ws);
  (void)hipFuncSetAttribute((const void*)mix_main,
                            hipFuncAttributeMaxDynamicSharedMemorySize, LDS_TOTAL);
  hipLaunchKernelGGL(mix_main, dim3(Bt / 64), dim3(256), LDS_TOTAL, stream,
                     mask, board, common_b, wdl_w, wdl_b, ws, out, Bt);
}

// Round 10
// 734.435 us; speedup vs baseline: 1.4596x; 1.2240x over previous
//
#include <hip/hip_runtime.h>
#include <hip/hip_bf16.h>
#include <stdint.h>

// ---------------------------------------------------------------------------
// MixModel fused kernel (MI355X / gfx950), round 10.
//
// r9 was latency-bound at 1 wave/SIMD (LDS 110KB -> 1 block/CU; all counters
// low). This round halves LDS via 2-phase step split so 2 blocks/CU fit:
//   bufA (30KB): layer jt0-4 / common i0-4;  bufB: jt5-8 / i5-8.
//   stage B while computing A; stage next A while computing B. No parity.
// Message bank (162 VGPR), bitmask static features, bias-in-weight-row-45,
// parity transpose scheme: unchanged (r9-proven). conv_common_w re-laid-out
// i-major to make the phase split contiguous.
// ---------------------------------------------------------------------------

typedef __attribute__((ext_vector_type(4))) float    f32x4;
typedef __attribute__((ext_vector_type(4))) _Float16 f16x4;
typedef __attribute__((ext_vector_type(8))) _Float16 f16x8;
typedef unsigned long long u64;
typedef unsigned int u32;

#define STEP_BYTES 55296            // 9 jt * 6 slices * 64 lanes * 16B
#define PHA_SZ     30720            // jt 0..4
#define PHB_SZ     24576            // jt 5..8
#define CMN_STRIDE 41472            // 9 i * (4*1024 + 512)
#define CPA_SZ     23040            // i 0..4
#define CPB_SZ     18432            // i 5..8
#define WS_LAYER   (54*STEP_BYTES)  // 2,985,984
#define LDS_TOTAL  (2*PHA_SZ)       // 61,440 -> 2 blocks/CU

__device__ __forceinline__ unsigned short f2h(float f) {
  return __builtin_bit_cast(unsigned short, (_Float16)f);
}
__device__ __forceinline__ u64 as_u64(f16x4 v) { return __builtin_bit_cast(u64, v); }
__device__ __forceinline__ f16x4 as_f16x4(u64 v) { return __builtin_bit_cast(f16x4, v); }

__device__ __forceinline__ f32x4 mfma16(f16x4 a, f16x4 b, f32x4 c) {
#if __has_builtin(__builtin_amdgcn_mfma_f32_16x16x16f16)
  return __builtin_amdgcn_mfma_f32_16x16x16f16(a, b, c, 0, 0, 0);
#else
  asm("v_mfma_f32_16x16x16_f16 %0, %1, %2, %0" : "+v"(c) : "v"(a), "v"(b));
  return c;
#endif
}

// static feature value for (sample b, position o, padded k-index kidx in [0,48))
// [0..8] mask row o | [9..17] board ch0 row o | [18..26] board ch1 row o
// [27..35] g0 (ch0 row 9) | [36..44] g1 (ch1 row 9) | [45..47] zero pad
__device__ __forceinline__ float static_feat(const float* __restrict__ mask,
                                             const float* __restrict__ board,
                                             int b, int o, int kidx) {
  if (kidx < 9)  return mask [b*81  + o*9 + kidx];
  if (kidx < 18) return board[b*180 +       o*9 + (kidx - 9)];
  if (kidx < 27) return board[b*180 + 90 +  o*9 + (kidx - 18)];
  if (kidx < 36) return board[b*180 +       81 + (kidx - 27)];
  if (kidx < 45) return board[b*180 + 90 +  81 + (kidx - 36)];
  return 0.f;
}

// async stage nbytes (16B-granular, nbytes/16 % 64 == 0) into LDS
__device__ __forceinline__ void stage_bytes(const unsigned char* __restrict__ src,
                                            unsigned char* dstlds, int nbytes, int tid) {
  const int n16 = nbytes / 16;
  const int ubase = tid & ~63;
  for (int k = 0; k * 256 < n16; ++k) {
    const int idx = k * 256 + tid;
    if (idx < n16) {  // wave-uniform (n16 % 64 == 0)
      __builtin_amdgcn_global_load_lds(
          (const __attribute__((address_space(1))) void*)(src + (size_t)idx * 16),
          (__attribute__((address_space(3))) void*)(dstlds + (size_t)(k * 256 + ubase) * 16),
          16, 0, 0);
    }
  }
}

// j-tile range [J0,J1) of one (layer,position) step; buf holds panel bytes
// starting at byte offset OFF of the step's A-panel.
template<int P, int O, int J0, int J1, int OFF>
__device__ __forceinline__ void jt_range(const unsigned char* __restrict__ buf,
    u64 (&msg)[9][9], const u64 (&msgc)[9], f16x4 st0, f16x4 st1, f16x4 stc, int lane)
{
  const unsigned char* abase = buf + (size_t)lane * 16 - OFF;
#pragma unroll
  for (int j = J0; j < J1; ++j) {
    f32x4 acc = 0.f;
#pragma unroll
    for (int sp = 0; sp < 6; ++sp) {
      const f16x8 af = *(const f16x8*)(abase + j * 6144 + sp * 1024);
      const f16x4 alo = __builtin_shufflevector(af, af, 0, 1, 2, 3);
      const f16x4 ahi = __builtin_shufflevector(af, af, 4, 5, 6, 7);
      const int c0 = 2 * sp, c1 = 2 * sp + 1;
      if (c0 == 0)      acc = mfma16(alo, st0, acc);
      else if (c0 == 2) acc = mfma16(alo, stc, acc);
      else              acc = mfma16(alo, as_f16x4(msgc[c0 - 3]), acc);
      if (c1 == 1)      acc = mfma16(ahi, st1, acc);
      else              acc = mfma16(ahi, as_f16x4(msgc[c1 - 3]), acc);
    }
    f16x4 h;
#pragma unroll
    for (int r = 0; r < 4; ++r)
      h[r] = (_Float16)fmaxf(acc[r], 0.f);
    if (P) msg[O][j] = as_u64(h); else msg[j][O] = as_u64(h);
  }
}

// one (layer,position) step with 2-phase staging. Precondition: phase A of
// this step staged into bufA (loads possibly in flight).
template<int P, int O>
__device__ __forceinline__ void do_step_layer(int base, const unsigned char* __restrict__ ws,
    unsigned char* bufA, unsigned char* bufB, u64 (&msg)[9][9],
    u64 sb, u32 sb8, f16x4 stc, int lane, int tid)
{
  const int step = base + P * 9 + O;

  asm volatile("s_waitcnt vmcnt(0)" ::: "memory");
  __syncthreads();
  stage_bytes(ws + (size_t)step * STEP_BYTES + PHA_SZ, bufB, PHB_SZ, tid);

  // rebuild position-O static fragments from the bitmask bank (values 0/1)
  f16x4 st0, st1;
  {
    const u32 byt = (O < 8) ? ((u32)(sb >> (O * 8)) & 0xFFu) : sb8;
#pragma unroll
    for (int e = 0; e < 4; ++e) {
      st0[e] = (_Float16)(float)((byt >> e) & 1u);
      st1[e] = (_Float16)(float)((byt >> (4 + e)) & 1u);
    }
  }
  // snapshot message chunks (read set == write set within this step)
  u64 msgc[9];
#pragma unroll
  for (int i = 0; i < 9; ++i)
    msgc[i] = P ? msg[O][i] : msg[i][O];

  jt_range<P, O, 0, 5, 0>(bufA, msg, msgc, st0, st1, stc, lane);

  asm volatile("s_waitcnt vmcnt(0)" ::: "memory");
  __syncthreads();
  if (step + 1 < 54)
    stage_bytes(ws + (size_t)(step + 1) * STEP_BYTES, bufA, PHA_SZ, tid);
  else
    stage_bytes(ws + WS_LAYER, bufA, CPA_SZ, tid);   // common mt=0 phase A

  jt_range<P, O, 5, 9, PHA_SZ>(bufB, msg, msgc, st0, st1, stc, lane);
}

__global__ __launch_bounds__(256, 1) void mix_main(
    const float* __restrict__ mask, const float* __restrict__ board,
    const float* __restrict__ common_b, const float* __restrict__ wdl_w,
    const float* __restrict__ wdl_b, const unsigned char* __restrict__ ws,
    float* __restrict__ out, int Bt)
{
  extern __shared__ unsigned char lds[];
  const int tid = threadIdx.x;
  const int lane = tid & 63;
  const int wid = tid >> 6;
  const int s15 = lane & 15, hq = lane >> 4;
  const int b0 = blockIdx.x * 64 + wid * 16;   // 16 samples per wave
  unsigned char* bufA = lds;
  unsigned char* bufB = lds + PHA_SZ;

  stage_bytes(ws, bufA, PHA_SZ, tid);   // prologue: phase A of step 0

  u64 msg[9][9];
#pragma unroll
  for (int a = 0; a < 9; ++a)
#pragma unroll
    for (int b = 0; b < 9; ++b) msg[a][b] = 0ull;

  // static bitmask bank: bit (o*8 + c*4 + e) of sb (o<8) / sb8 (o=8)
  u64 sb = 0ull;
  u32 sb8 = 0u;
  {
    const int b = b0 + s15;
#pragma unroll
    for (int o = 0; o < 9; ++o)
#pragma unroll
      for (int e = 0; e < 4; ++e) {
        const u32 bit0 = static_feat(mask, board, b, o,      4 * hq + e) > 0.5f;
        const u32 bit1 = static_feat(mask, board, b, o, 16 + 4 * hq + e) > 0.5f;
        if (o < 8) sb |= ((u64)bit0 << (o * 8 + e)) | ((u64)bit1 << (o * 8 + 4 + e));
        else       sb8 |= (bit0 << e) | (bit1 << (4 + e));
      }
  }

  // position-independent chunk 2 (g0 tail + g1); pad lane k=45 carries 1.0
  f16x4 stc;
  {
    const int b = b0 + s15;
#pragma unroll
    for (int e = 0; e < 4; ++e) {
      const int kidx = 32 + 4 * hq + e;
      stc[e] = (_Float16)((kidx == 45) ? 1.f : static_feat(mask, board, b, 0, kidx));
    }
  }

#define DO_POS(P, O) do_step_layer<P, O>(base, ws, bufA, bufB, msg, sb, sb8, stc, lane, tid);
  for (int dp = 0; dp < 3; ++dp) {
    const int base = dp * 18;
    DO_POS(0,0) DO_POS(0,1) DO_POS(0,2) DO_POS(0,3) DO_POS(0,4)
    DO_POS(0,5) DO_POS(0,6) DO_POS(0,7) DO_POS(0,8)
    DO_POS(1,0) DO_POS(1,1) DO_POS(1,2) DO_POS(1,3) DO_POS(1,4)
    DO_POS(1,5) DO_POS(1,6) DO_POS(1,7) DO_POS(1,8)
  }
#undef DO_POS

  // ---- common layer: (B x 1296) @ (1296 x 145), 10 M-tiles, 2-phase ----
  float pw[3] = {0.f, 0.f, 0.f};
  for (int mt = 0; mt < 10; ++mt) {
    asm volatile("s_waitcnt vmcnt(0)" ::: "memory");
    __syncthreads();
    stage_bytes(ws + WS_LAYER + (size_t)mt * CMN_STRIDE + CPA_SZ, bufB, CPB_SZ, tid);
    f32x4 a0 = 0.f;
#pragma unroll
    for (int i = 0; i < 5; ++i) {
      const unsigned char* base = bufA + i * 4608;
#pragma unroll
      for (int p = 0; p < 4; ++p) {
        const f16x8 af = *(const f16x8*)(base + p * 1024 + (size_t)lane * 16);
        const f16x4 alo = __builtin_shufflevector(af, af, 0, 1, 2, 3);
        const f16x4 ahi = __builtin_shufflevector(af, af, 4, 5, 6, 7);
        a0 = mfma16(alo, as_f16x4(msg[i][2 * p]),     a0);
        a0 = mfma16(ahi, as_f16x4(msg[i][2 * p + 1]), a0);
      }
      const f16x4 al = *(const f16x4*)(base + 4096 + (size_t)lane * 8);
      a0 = mfma16(al, as_f16x4(msg[i][8]), a0);
    }
    asm volatile("s_waitcnt vmcnt(0)" ::: "memory");
    __syncthreads();
    if (mt + 1 < 10)
      stage_bytes(ws + WS_LAYER + (size_t)(mt + 1) * CMN_STRIDE, bufA, CPA_SZ, tid);
#pragma unroll
    for (int i = 5; i < 9; ++i) {
      const unsigned char* base = bufB + i * 4608 - CPA_SZ;
#pragma unroll
      for (int p = 0; p < 4; ++p) {
        const f16x8 af = *(const f16x8*)(base + p * 1024 + (size_t)lane * 16);
        const f16x4 alo = __builtin_shufflevector(af, af, 0, 1, 2, 3);
        const f16x4 ahi = __builtin_shufflevector(af, af, 4, 5, 6, 7);
        a0 = mfma16(alo, as_f16x4(msg[i][2 * p]),     a0);
        a0 = mfma16(ahi, as_f16x4(msg[i][2 * p + 1]), a0);
      }
      const f16x4 al = *(const f16x4*)(base + 4096 + (size_t)lane * 8);
      a0 = mfma16(al, as_f16x4(msg[i][8]), a0);
    }
#pragma unroll
    for (int r = 0; r < 4; ++r) {
      const int c = mt * 16 + 4 * hq + r;
      const float bias = (c < 145) ? common_b[c] : 0.f;
      const float v0 = a0[r] + bias;
      if (c < 81) {  // policy (no relu)
        out[(size_t)3 * Bt + (size_t)(b0 + s15) * 81 + c] = v0;
      } else if (c < 145) {  // wdl hidden: relu then tiny matmul accumulation
        const float h0 = fmaxf(v0, 0.f);
        const int cc = c - 81;
#pragma unroll
        for (int w = 0; w < 3; ++w)
          pw[w] += h0 * wdl_w[cc * 3 + w];
      }
    }
  }

  // reduce wdl partials across the 4 lane-quarters (same sample col)
#pragma unroll
  for (int w = 0; w < 3; ++w) {
    float v0 = pw[w];
    v0 += __shfl_xor(v0, 16, 64); v0 += __shfl_xor(v0, 32, 64);
    if (hq == 0)
      out[(size_t)(b0 + s15) * 3 + w] = v0 + wdl_b[w];
  }
}

// ---- prologue: layer weights -> fp16 A-fragment order -----------------------
// [d*9+o][jt 9][slice 6][lane 64] x 16B ; e<4 -> kc=2s, e>=4 -> kc=2s+1,
// within-chunk k = 4*hq + (e&3). kidx: 0..44 static, 45 = BIAS row, 46..47
// zero, >=48 -> message k = kidx-3.
__global__ __launch_bounds__(256) void conv_layer_w(const float* __restrict__ lw,
                                                    const float* __restrict__ lb,
                                                    unsigned char* __restrict__ dst) {
  const int gid = blockIdx.x * 256 + threadIdx.x;
  if (gid >= 54 * 9 * 6 * 64) return;
  const int lane = gid & 63;
  const int t = gid >> 6;
  const int kp = t % 6, t2 = t / 6;
  const int jp = t2 % 9, dop = t2 / 9;
  const int m = lane & 15, hq = lane >> 4;
  unsigned short v[8];
#pragma unroll
  for (int e = 0; e < 8; ++e) {
    const int kc = kp * 2 + (e >> 2);
    const int kidx = kc * 16 + 4 * hq + (e & 3);
    float f = 0.f;
    if (kidx < 45)        f = lw[((size_t)dop * 189 + kidx) * 144 + jp * 16 + m];
    else if (kidx == 45)  f = lb[(size_t)dop * 144 + jp * 16 + m];
    else if (kidx >= 48)  f = lw[((size_t)dop * 189 + (kidx - 3)) * 144 + jp * 16 + m];
    v[e] = f2h(f);
  }
  const u32 w0 = (u32)v[0] | ((u32)v[1] << 16);
  const u32 w1 = (u32)v[2] | ((u32)v[3] << 16);
  const u32 w2 = (u32)v[4] | ((u32)v[5] << 16);
  const u32 w3 = (u32)v[6] | ((u32)v[7] << 16);
  *(uint4*)(dst + (size_t)gid * 16) = make_uint4(w0, w1, w2, w3);
}

// ---- prologue: common weights -> fp16 A-fragment order, i-major -------------
// per mt (stride 41472): per i (stride 4608): p=0..3 pair-units (1KB each,
// ci = i*9+2p, i*9+2p+1) then leftover (512B, ci = i*9+8). c padded 145->160.
__global__ __launch_bounds__(256) void conv_common_w(const float* __restrict__ cw,
                                                     unsigned char* __restrict__ dst) {
  const int gid = blockIdx.x * 256 + threadIdx.x;
  const int NPAIR = 10 * 36 * 64;
  if (gid < NPAIR) {
    const int lane = gid & 63;
    const int t = gid >> 6;
    const int p = t % 4, t2 = t / 4;
    const int i = t2 % 9, mt = t2 / 9;
    const int m = lane & 15, hq = lane >> 4;
    const int c = mt * 16 + m;
    unsigned short v[8];
#pragma unroll
    for (int e = 0; e < 8; ++e) {
      const int ci = i * 9 + 2 * p + (e >> 2);
      const int k = ci * 16 + 4 * hq + (e & 3);
      v[e] = f2h((c < 145) ? cw[(size_t)k * 145 + c] : 0.f);
    }
    const u32 w0 = (u32)v[0] | ((u32)v[1] << 16);
    const u32 w1 = (u32)v[2] | ((u32)v[3] << 16);
    const u32 w2 = (u32)v[4] | ((u32)v[5] << 16);
    const u32 w3 = (u32)v[6] | ((u32)v[7] << 16);
    *(uint4*)(dst + (size_t)WS_LAYER + (size_t)mt * CMN_STRIDE + (size_t)i * 4608
              + (size_t)p * 1024 + (size_t)lane * 16) = make_uint4(w0, w1, w2, w3);
  } else if (gid < NPAIR + 10 * 9 * 64) {
    const int g = gid - NPAIR;
    const int lane = g & 63;
    const int t = g >> 6;
    const int i = t % 9, mt = t / 9;
    const int m = lane & 15, hq = lane >> 4;
    const int c = mt * 16 + m;
    unsigned short v[4];
#pragma unroll
    for (int e = 0; e < 4; ++e) {
      const int k = (i * 9 + 8) * 16 + 4 * hq + e;
      v[e] = f2h((c < 145) ? cw[(size_t)k * 145 + c] : 0.f);
    }
    const u32 w0 = (u32)v[0] | ((u32)v[1] << 16);
    const u32 w1 = (u32)v[2] | ((u32)v[3] << 16);
    *(uint2*)(dst + (size_t)WS_LAYER + (size_t)mt * CMN_STRIDE + (size_t)i * 4608
              + 4096 + (size_t)lane * 8) = make_uint2(w0, w1);
  }
}

extern "C" void kernel_launch(void* const* d_in, const int* in_sizes, int n_in,
                              void* d_out, int out_size, void* d_ws, size_t ws_size,
                              hipStream_t stream) {
  const float* mask     = (const float*)d_in[0];
  const float* board    = (const float*)d_in[1];
  const float* layer_w  = (const float*)d_in[2];
  const float* layer_b  = (const float*)d_in[3];
  const float* common_w = (const float*)d_in[4];
  const float* common_b = (const float*)d_in[5];
  const float* wdl_w    = (const float*)d_in[6];
  const float* wdl_b    = (const float*)d_in[7];
  float* out = (float*)d_out;
  unsigned char* ws = (unsigned char*)d_ws;
  const int Bt = in_sizes[0] / 81;   // 65536

  hipLaunchKernelGGL(conv_layer_w, dim3((54 * 9 * 6 * 64) / 256), dim3(256), 0, stream,
                     layer_w, layer_b, ws);
  hipLaunchKernelGGL(conv_common_w, dim3((10 * (36 + 9) * 64 + 255) / 256), dim3(256),
                     0, stream, common_w, ws);
  (void)hipFuncSetAttribute((const void*)mix_main,
                            hipFuncAttributeMaxDynamicSharedMemorySize, LDS_TOTAL);
  hipLaunchKernelGGL(mix_main, dim3(Bt / 64), dim3(256), LDS_TOTAL, stream,
                     mask, board, common_b, wdl_w, wdl_b, ws, out, Bt);
}